// Round 1
// baseline (411.129 us; speedup 1.0000x reference)
//
#include <hip/hip_runtime.h>
#include <stdint.h>
#include <math.h>

#define N_NODES 20000
#define C_IN 128
#define C_OUT 64
#define T_STEPS 8
#define NE 160000

// ---------------- K1: per-channel partial sums (fp64) ----------------
__global__ __launch_bounds__(256) void stats_kernel(const float* __restrict__ x,
                                                    double* __restrict__ dsum,
                                                    double* __restrict__ dsq) {
  const int P = N_NODES * C_IN;  // (n,c) pairs; each owns 8 contiguous floats (t)
  int tid = threadIdx.x;
  int gid = blockIdx.x * 256 + tid;
  double s = 0.0, q = 0.0;
  for (int p = gid; p < P; p += 256 * 256) {   // stride 65536 % 128 == 0 -> c constant per thread
    const float4* xp = (const float4*)(x + (size_t)p * 8);
    float4 a = xp[0], b = xp[1];
    float v[8] = {a.x, a.y, a.z, a.w, b.x, b.y, b.z, b.w};
#pragma unroll
    for (int j = 0; j < 8; ++j) { double d = (double)v[j]; s += d; q += d * d; }
  }
  __shared__ double ls[256], lq[256];
  ls[tid] = s; lq[tid] = q;
  __syncthreads();
  if (tid < 128) {  // tid and tid+128 share channel c==tid
    dsum[tid * 256 + blockIdx.x] = ls[tid] + ls[tid + 128];
    dsq [tid * 256 + blockIdx.x] = lq[tid] + lq[tid + 128];
  }
}

// ---------------- K2: finalize per-channel scale/shift ----------------
__global__ __launch_bounds__(256) void finalize_kernel(const double* __restrict__ dsum,
                                                       const double* __restrict__ dsq,
                                                       const float* __restrict__ gamma,
                                                       const float* __restrict__ beta,
                                                       double* __restrict__ adbl,
                                                       double* __restrict__ bdbl) {
  int c = blockIdx.x, tid = threadIdx.x;
  __shared__ double ls[256], lq[256];
  ls[tid] = dsum[c * 256 + tid];
  lq[tid] = dsq [c * 256 + tid];
  __syncthreads();
  for (int o = 128; o > 0; o >>= 1) {
    if (tid < o) { ls[tid] += ls[tid + o]; lq[tid] += lq[tid + o]; }
    __syncthreads();
  }
  if (tid == 0) {
    const double cnt = (double)N_NODES * T_STEPS;
    double mean = ls[0] / cnt;
    double var  = lq[0] / cnt - mean * mean;
    double ai = (double)gamma[c] / sqrt(var + 1e-5);
    adbl[c] = ai;
    bdbl[c] = (double)beta[c] - mean * ai;
  }
}

// ---------------- K3: LIF recurrence (fp64) + bit-pack spikes ----------------
__global__ __launch_bounds__(256) void lif_kernel(const float* __restrict__ x,
                                                  const double* __restrict__ adbl,
                                                  const double* __restrict__ bdbl,
                                                  unsigned char* __restrict__ spk) {
  int p = blockIdx.x * 256 + threadIdx.x;  // exactly N*C threads
  int c = p & (C_IN - 1);
  const float4* xp = (const float4*)(x + (size_t)p * 8);
  float4 a4 = xp[0], b4 = xp[1];
  float v[8] = {a4.x, a4.y, a4.z, a4.w, b4.x, b4.y, b4.z, b4.w};
  double a = adbl[c], bb = bdbl[c];
  double mem = 0.0, sp = 0.0;
  unsigned byte = 0;
#pragma unroll
  for (int t = 0; t < 8; ++t) {
    double h = a * (double)v[t] + bb;
    mem = mem * (0.2 * (1.0 - sp)) + h;   // mem*DECAY*(1-sp) + inp
    int fire = mem > 0.5;
    sp = fire ? 1.0 : 0.0;
    byte |= (unsigned)fire << t;
  }
  spk[p] = (unsigned char)byte;
}

// ---------------- CSR build ----------------
__global__ __launch_bounds__(256) void deg_kernel(const int* __restrict__ ei, int* __restrict__ deg) {
  int e = blockIdx.x * 256 + threadIdx.x;
  if (e < NE) atomicAdd(&deg[ei[NE + e]], 1);
}

__global__ __launch_bounds__(256) void dinv_kernel(const int* __restrict__ deg, float* __restrict__ dinv) {
  int n = blockIdx.x * 256 + threadIdx.x;
  if (n < N_NODES) {
    int d = deg[n];
    dinv[n] = d > 0 ? (float)(1.0 / sqrt((double)d)) : 0.f;
  }
}

__global__ __launch_bounds__(256) void scan_kernel(const int* __restrict__ deg,
                                                   int* __restrict__ offs,
                                                   int* __restrict__ cursor) {
  __shared__ int wsum[4];
  int tid = threadIdx.x, lane = tid & 63, w = tid >> 6;
  int carry = 0;
  for (int base = 0; base < N_NODES; base += 256) {
    int i = base + tid;
    int v = (i < N_NODES) ? deg[i] : 0;
    int s = v;
#pragma unroll
    for (int o = 1; o < 64; o <<= 1) {
      int u = __shfl_up(s, o);
      if (lane >= o) s += u;
    }
    if (lane == 63) wsum[w] = s;
    __syncthreads();
    int wpre = 0;
    for (int j = 0; j < w; ++j) wpre += wsum[j];
    int excl = carry + wpre + (s - v);
    if (i < N_NODES) { offs[i] = excl; cursor[i] = excl; }
    carry += wsum[0] + wsum[1] + wsum[2] + wsum[3];
    __syncthreads();
  }
  if (tid == 0) offs[N_NODES] = carry;
}

__global__ __launch_bounds__(256) void fill_kernel(const int* __restrict__ ei,
                                                   int* __restrict__ cursor,
                                                   int* __restrict__ csr) {
  int e = blockIdx.x * 256 + threadIdx.x;
  if (e < NE) {
    int pos = atomicAdd(&cursor[ei[NE + e]], 1);
    csr[pos] = ei[e];
  }
}

// ---------------- stacked transposed weights WT[k][d], k<128 -> W0, else W1 ----------------
__global__ __launch_bounds__(256) void wt_kernel(const float* __restrict__ W0,
                                                 const float* __restrict__ W1,
                                                 float* __restrict__ WT) {
  int i = blockIdx.x * 256 + threadIdx.x;  // 256*64
  int k = i >> 6, d = i & 63;
  WT[k * 64 + d] = (k < 128) ? W0[d * 128 + k] : W1[d * 128 + (k - 128)];
}

// ---------------- fused: aggregate (CSR gather of packed spikes) + GEMM + bias ----------------
// Block handles 4 nodes. LDS B[k][col]: k in [0,256) (128 spike rows + 128 agg rows),
// col = nl*8 + t (32 cols). Row stride 36 floats (16B-aligned, breaks bank pow2).
__global__ __launch_bounds__(256) void main_kernel(const unsigned char* __restrict__ spk,
                                                   const int* __restrict__ offs,
                                                   const int* __restrict__ csr,
                                                   const float* __restrict__ dinv,
                                                   const float* __restrict__ WT,
                                                   const float* __restrict__ bias,
                                                   float* __restrict__ out) {
  __shared__ float B[256 * 36];
  int n0 = blockIdx.x * 4;
  int tid = threadIdx.x;

  // Phase A: expand this block's own packed spikes into B rows [0,128)
#pragma unroll
  for (int it = 0; it < 2; ++it) {
    int idx = tid + it * 256;        // 0..511 = 4 nodes x 128 channels
    int c = idx & 127, nl = idx >> 7;
    unsigned byte = spk[(size_t)(n0 + nl) * 128 + c];
    float4 lo = {(float)(byte & 1), (float)((byte >> 1) & 1),
                 (float)((byte >> 2) & 1), (float)((byte >> 3) & 1)};
    float4 hi = {(float)((byte >> 4) & 1), (float)((byte >> 5) & 1),
                 (float)((byte >> 6) & 1), (float)((byte >> 7) & 1)};
    *(float4*)&B[c * 36 + nl * 8]     = lo;
    *(float4*)&B[c * 36 + nl * 8 + 4] = hi;
  }

  // Phase B: wave w aggregates incoming edges of node n0+w into B rows [128,256)
  int w = tid >> 6, lane = tid & 63;
  int node = n0 + w;
  float acc[16];
#pragma unroll
  for (int j = 0; j < 16; ++j) acc[j] = 0.f;
  int e0 = offs[node], e1 = offs[node + 1];
  const unsigned short* sp16 = (const unsigned short*)spk;  // lane covers c=2*lane, 2*lane+1
  for (int e = e0; e < e1; ++e) {
    int src = csr[e];
    float wt = dinv[src];
    unsigned bits = sp16[(size_t)src * 64 + lane];
#pragma unroll
    for (int j = 0; j < 16; ++j) acc[j] += ((bits >> j) & 1) ? wt : 0.f;
  }
  float sc = dinv[node];  // dinv[dst] factored out of the edge loop
  int c0 = 2 * lane;
  float4 v0 = {acc[0] * sc, acc[1] * sc, acc[2] * sc, acc[3] * sc};
  float4 v1 = {acc[4] * sc, acc[5] * sc, acc[6] * sc, acc[7] * sc};
  float4 v2 = {acc[8] * sc, acc[9] * sc, acc[10] * sc, acc[11] * sc};
  float4 v3 = {acc[12] * sc, acc[13] * sc, acc[14] * sc, acc[15] * sc};
  *(float4*)&B[(128 + c0) * 36 + w * 8]     = v0;
  *(float4*)&B[(128 + c0) * 36 + w * 8 + 4] = v1;
  *(float4*)&B[(129 + c0) * 36 + w * 8]     = v2;
  *(float4*)&B[(129 + c0) * 36 + w * 8 + 4] = v3;
  __syncthreads();

  // Phase C: out[d][col] = sum_k WT[k][d] * B[k][col]; thread tile 2d x 4cols
  int dt = tid & 31, ct = tid >> 5;
  const float2* A2 = (const float2*)WT;
  float4 acc0 = {0, 0, 0, 0}, acc1 = {0, 0, 0, 0};
#pragma unroll 8
  for (int k = 0; k < 256; ++k) {
    float2 a = A2[k * 32 + dt];
    float4 bv = *(const float4*)&B[k * 36 + 4 * ct];
    acc0.x += a.x * bv.x; acc0.y += a.x * bv.y; acc0.z += a.x * bv.z; acc0.w += a.x * bv.w;
    acc1.x += a.y * bv.x; acc1.y += a.y * bv.y; acc1.z += a.y * bv.z; acc1.w += a.y * bv.w;
  }
  int d0 = 2 * dt, nl = ct >> 1, t0 = (ct & 1) * 4;
  float b0 = bias[d0], b1 = bias[d0 + 1];
  float4 o0 = {acc0.x + b0, acc0.y + b0, acc0.z + b0, acc0.w + b0};
  float4 o1 = {acc1.x + b1, acc1.y + b1, acc1.z + b1, acc1.w + b1};
  size_t base = (size_t)(n0 + nl) * 512;
  *(float4*)&out[base + d0 * 8 + t0]       = o0;
  *(float4*)&out[base + (d0 + 1) * 8 + t0] = o1;
}

extern "C" void kernel_launch(void* const* d_in, const int* in_sizes, int n_in,
                              void* d_out, int out_size, void* d_ws, size_t ws_size,
                              hipStream_t stream) {
  const float* x     = (const float*)d_in[0];
  const int*   ei    = (const int*)d_in[1];   // [2, E] int32
  const float* gamma = (const float*)d_in[2];
  const float* beta  = (const float*)d_in[3];
  const float* W0    = (const float*)d_in[4];
  const float* W1    = (const float*)d_in[5];
  const float* bias  = (const float*)d_in[6];
  float* out = (float*)d_out;

  char* ws = (char*)d_ws;
  size_t off = 0;
  auto alloc = [&](size_t bytes) -> void* {
    void* p = ws + off;
    off = (off + bytes + 255) & ~(size_t)255;
    return p;
  };
  double* dsum = (double*)alloc(128 * 256 * 8);
  double* dsq  = (double*)alloc(128 * 256 * 8);
  double* adbl = (double*)alloc(128 * 8);
  double* bdbl = (double*)alloc(128 * 8);
  int*    deg  = (int*)alloc(N_NODES * 4);
  float*  dinv = (float*)alloc(N_NODES * 4);
  int*    offs = (int*)alloc((N_NODES + 1) * 4);
  int*    curs = (int*)alloc(N_NODES * 4);
  int*    csr  = (int*)alloc(NE * 4);
  unsigned char* spk = (unsigned char*)alloc((size_t)N_NODES * C_IN);
  float*  WT   = (float*)alloc(256 * 64 * 4);

  hipMemsetAsync(deg, 0, N_NODES * 4, stream);

  stats_kernel<<<256, 256, 0, stream>>>(x, dsum, dsq);
  finalize_kernel<<<128, 256, 0, stream>>>(dsum, dsq, gamma, beta, adbl, bdbl);
  lif_kernel<<<(N_NODES * C_IN) / 256, 256, 0, stream>>>(x, adbl, bdbl, spk);
  deg_kernel<<<(NE + 255) / 256, 256, 0, stream>>>(ei, deg);
  dinv_kernel<<<(N_NODES + 255) / 256, 256, 0, stream>>>(deg, dinv);
  scan_kernel<<<1, 256, 0, stream>>>(deg, offs, curs);
  fill_kernel<<<(NE + 255) / 256, 256, 0, stream>>>(ei, curs, csr);
  wt_kernel<<<64, 256, 0, stream>>>(W0, W1, WT);
  main_kernel<<<N_NODES / 4, 256, 0, stream>>>(spk, offs, csr, dinv, WT, bias, out);
}

// Round 2
// 261.108 us; speedup vs baseline: 1.5746x; 1.5746x over previous
//
#include <hip/hip_runtime.h>
#include <stdint.h>
#include <math.h>

#define N_NODES 20000
#define C_IN 128
#define C_OUT 64
#define T_STEPS 8
#define NE 160000
#define NB_STATS 1024
#define NPB 8        // nodes per block in main kernel
#define RPAD 264     // Bls row stride (bf16 units): 256 + 8 pad

typedef __attribute__((ext_vector_type(8))) short short8;
typedef __attribute__((ext_vector_type(4))) float f32x4;

static __device__ __forceinline__ unsigned short bf16_rne(float f) {
  unsigned u = __builtin_bit_cast(unsigned, f);
  return (unsigned short)((u + 0x7FFFu + ((u >> 16) & 1u)) >> 16);
}

// ---------------- K1: per-channel partial sums (fp64) ----------------
__global__ __launch_bounds__(256) void stats_kernel(const float* __restrict__ x,
                                                    double* __restrict__ dsum,
                                                    double* __restrict__ dsq) {
  const int P = N_NODES * C_IN;
  int tid = threadIdx.x;
  int gid = blockIdx.x * 256 + tid;
  double s = 0.0, q = 0.0;
  for (int p = gid; p < P; p += 256 * NB_STATS) {  // stride % 128 == 0 -> c constant
    const float4* xp = (const float4*)(x + (size_t)p * 8);
    float4 a = xp[0], b = xp[1];
    float v[8] = {a.x, a.y, a.z, a.w, b.x, b.y, b.z, b.w};
#pragma unroll
    for (int j = 0; j < 8; ++j) { double d = (double)v[j]; s += d; q += d * d; }
  }
  __shared__ double ls[256], lq[256];
  ls[tid] = s; lq[tid] = q;
  __syncthreads();
  if (tid < 128) {  // tid and tid+128 share channel c==tid
    dsum[tid * NB_STATS + blockIdx.x] = ls[tid] + ls[tid + 128];
    dsq [tid * NB_STATS + blockIdx.x] = lq[tid] + lq[tid + 128];
  }
}

// ---------------- K2: finalize per-channel scale/shift ----------------
__global__ __launch_bounds__(256) void finalize_kernel(const double* __restrict__ dsum,
                                                       const double* __restrict__ dsq,
                                                       const float* __restrict__ gamma,
                                                       const float* __restrict__ beta,
                                                       double* __restrict__ adbl,
                                                       double* __restrict__ bdbl) {
  int c = blockIdx.x, tid = threadIdx.x;
  __shared__ double ls[256], lq[256];
  double s = 0.0, q = 0.0;
#pragma unroll
  for (int i = 0; i < NB_STATS / 256; ++i) {
    s += dsum[c * NB_STATS + tid + 256 * i];
    q += dsq [c * NB_STATS + tid + 256 * i];
  }
  ls[tid] = s; lq[tid] = q;
  __syncthreads();
  for (int o = 128; o > 0; o >>= 1) {
    if (tid < o) { ls[tid] += ls[tid + o]; lq[tid] += lq[tid + o]; }
    __syncthreads();
  }
  if (tid == 0) {
    const double cnt = (double)N_NODES * T_STEPS;
    double mean = ls[0] / cnt;
    double var  = lq[0] / cnt - mean * mean;
    double ai = (double)gamma[c] / sqrt(var + 1e-5);
    adbl[c] = ai;
    bdbl[c] = (double)beta[c] - mean * ai;
  }
}

// ---------------- K3: LIF recurrence (fp64) + bit-pack spikes ----------------
__global__ __launch_bounds__(256) void lif_kernel(const float* __restrict__ x,
                                                  const double* __restrict__ adbl,
                                                  const double* __restrict__ bdbl,
                                                  unsigned char* __restrict__ spk) {
  int p = blockIdx.x * 256 + threadIdx.x;  // exactly N*C threads
  int c = p & (C_IN - 1);
  const float4* xp = (const float4*)(x + (size_t)p * 8);
  float4 a4 = xp[0], b4 = xp[1];
  float v[8] = {a4.x, a4.y, a4.z, a4.w, b4.x, b4.y, b4.z, b4.w};
  double a = adbl[c], bb = bdbl[c];
  double mem = 0.0, sp = 0.0;
  unsigned byte = 0;
#pragma unroll
  for (int t = 0; t < 8; ++t) {
    double h = a * (double)v[t] + bb;
    mem = mem * (0.2 * (1.0 - sp)) + h;
    int fire = mem > 0.5;
    sp = fire ? 1.0 : 0.0;
    byte |= (unsigned)fire << t;
  }
  spk[p] = (unsigned char)byte;
}

// ---------------- CSR build ----------------
__global__ __launch_bounds__(256) void deg_kernel(const int* __restrict__ ei, int* __restrict__ deg) {
  int e = blockIdx.x * 256 + threadIdx.x;
  if (e < NE) atomicAdd(&deg[ei[NE + e]], 1);
}

__global__ __launch_bounds__(1024) void scan_kernel(const int* __restrict__ deg,
                                                    int* __restrict__ offs,
                                                    int* __restrict__ cursor,
                                                    float* __restrict__ dinv) {
  __shared__ int wsum[16];
  int tid = threadIdx.x, lane = tid & 63, w = tid >> 6;
  int carry = 0;
  for (int base = 0; base < N_NODES; base += 1024) {
    int i = base + tid;
    int v = (i < N_NODES) ? deg[i] : 0;
    int s = v;
#pragma unroll
    for (int o = 1; o < 64; o <<= 1) {
      int u = __shfl_up(s, o);
      if (lane >= o) s += u;
    }
    if (lane == 63) wsum[w] = s;
    __syncthreads();
    int wpre = 0;
    for (int j = 0; j < w; ++j) wpre += wsum[j];
    int excl = carry + wpre + (s - v);
    if (i < N_NODES) {
      offs[i] = excl; cursor[i] = excl;
      dinv[i] = v > 0 ? (float)(1.0 / sqrt((double)v)) : 0.f;
    }
    int tot = 0;
#pragma unroll
    for (int j = 0; j < 16; ++j) tot += wsum[j];
    carry += tot;
    __syncthreads();
  }
  if (tid == 0) offs[N_NODES] = carry;
}

__global__ __launch_bounds__(256) void fill_kernel(const int* __restrict__ ei,
                                                   int* __restrict__ cursor,
                                                   int* __restrict__ csr) {
  int e = blockIdx.x * 256 + threadIdx.x;
  if (e < NE) {
    int pos = atomicAdd(&cursor[ei[NE + e]], 1);
    csr[pos] = ei[e];
  }
}

// ---------------- WTb: bf16 A-fragments in MFMA lane order ----------------
// layout: [(mt*8+kt)*64 + lane] * 8 bf16 ; A[m][k] with m=mt*16+(lane&15), k=kt*32+(lane>>4)*8+j
__global__ __launch_bounds__(256) void wtb_kernel(const float* __restrict__ W0,
                                                  const float* __restrict__ W1,
                                                  unsigned short* __restrict__ WTb) {
  int idx = blockIdx.x * 256 + threadIdx.x;  // 2048 threads
  int mt = idx >> 9, kt = (idx >> 6) & 7, lane = idx & 63;
  int m = mt * 16 + (lane & 15);
  int kb = kt * 32 + (lane >> 4) * 8;
  unsigned short frag[8];
#pragma unroll
  for (int j = 0; j < 8; ++j) {
    int k = kb + j;
    float wv = (k < 128) ? W0[m * 128 + k] : W1[m * 128 + (k - 128)];
    frag[j] = bf16_rne(wv);
  }
  *(uint4*)&WTb[(size_t)idx * 8] = *(uint4*)frag;
}

// ---------------- fused: spike expand + edge aggregate + MFMA GEMM + bias ----------------
__global__ __launch_bounds__(256) void main_kernel(const unsigned char* __restrict__ spk,
                                                   const int* __restrict__ offs,
                                                   const int* __restrict__ csr,
                                                   const float* __restrict__ dinv,
                                                   const unsigned short* __restrict__ WTb,
                                                   const float* __restrict__ bias,
                                                   float* __restrict__ out) {
  __shared__ unsigned short Bls[64 * RPAD];  // [col][k] bf16, col=nl*8+t, k=0..255
  int tid = threadIdx.x;
  int n0 = blockIdx.x * NPB;
  int lane = tid & 63, w = tid >> 6;

  // Phase A: expand own spikes into k in [0,128)
#pragma unroll
  for (int it = 0; it < 2; ++it) {
    int task = tid + it * 256;           // 512 = 64 cols x 8 channel-groups
    int col = task & 63, cg = task >> 6;
    int node = n0 + (col >> 3), t = col & 7;
    uint4 u = *(const uint4*)(spk + (size_t)node * 128 + cg * 16);
    unsigned ua[4] = {u.x, u.y, u.z, u.w};
    unsigned ow[8];
#pragma unroll
    for (int i = 0; i < 4; ++i) {
      unsigned v = (ua[i] >> t) & 0x01010101u;
      unsigned s0 = (v & 1u)         ? 0x3F80u : 0u;
      unsigned s1 = ((v >> 8) & 1u)  ? 0x3F800000u : 0u;
      unsigned s2 = ((v >> 16) & 1u) ? 0x3F80u : 0u;
      unsigned s3 = (v >> 24)        ? 0x3F800000u : 0u;
      ow[i * 2]     = s0 | s1;
      ow[i * 2 + 1] = s2 | s3;
    }
    uint4 o0 = {ow[0], ow[1], ow[2], ow[3]};
    uint4 o1 = {ow[4], ow[5], ow[6], ow[7]};
    *(uint4*)&Bls[col * RPAD + cg * 16]     = o0;
    *(uint4*)&Bls[col * RPAD + cg * 16 + 8] = o1;
  }

  // Phase B: each wave aggregates 2 nodes (sequential), 2 channels/lane, into k in [128,256)
  const unsigned short* sp16 = (const unsigned short*)spk;
#pragma unroll 1
  for (int nn = 0; nn < 2; ++nn) {
    int node = n0 + w * 2 + nn;
    int e0 = offs[node], e1 = offs[node + 1];
    float acc[16];
#pragma unroll
    for (int j = 0; j < 16; ++j) acc[j] = 0.f;
    for (int e = e0; e < e1; ++e) {
      int src = csr[e];
      float wt = dinv[src];
      unsigned bits = sp16[(size_t)src * 64 + lane];
#pragma unroll
      for (int j = 0; j < 16; ++j)
        acc[j] = fmaf((float)((bits >> j) & 1u), wt, acc[j]);
    }
    float sc = dinv[node];
    int colb = (w * 2 + nn) * 8;
    int c0 = 2 * lane;
#pragma unroll
    for (int t = 0; t < 8; ++t) {
      unsigned pk = (unsigned)bf16_rne(acc[t] * sc) |
                    ((unsigned)bf16_rne(acc[8 + t] * sc) << 16);
      *(unsigned*)&Bls[(colb + t) * RPAD + 128 + c0] = pk;
    }
  }
  __syncthreads();

  // Phase C: D[m=d][n=col] = sum_k WT[m][k] * B[k][n]  via 16x16x32 bf16 MFMA
  int q = lane >> 4, l16 = lane & 15;
  int col = w * 16 + l16;
  const short8* WT8 = (const short8*)WTb;
  f32x4 acc0 = {0, 0, 0, 0}, acc1 = {0, 0, 0, 0}, acc2 = {0, 0, 0, 0}, acc3 = {0, 0, 0, 0};
#pragma unroll
  for (int kt = 0; kt < 8; ++kt) {
    short8 b = *(const short8*)&Bls[col * RPAD + kt * 32 + q * 8];
    acc0 = __builtin_amdgcn_mfma_f32_16x16x32_bf16(WT8[(0 * 8 + kt) * 64 + lane], b, acc0, 0, 0, 0);
    acc1 = __builtin_amdgcn_mfma_f32_16x16x32_bf16(WT8[(1 * 8 + kt) * 64 + lane], b, acc1, 0, 0, 0);
    acc2 = __builtin_amdgcn_mfma_f32_16x16x32_bf16(WT8[(2 * 8 + kt) * 64 + lane], b, acc2, 0, 0, 0);
    acc3 = __builtin_amdgcn_mfma_f32_16x16x32_bf16(WT8[(3 * 8 + kt) * 64 + lane], b, acc3, 0, 0, 0);
  }

  // Epilogue: C/D layout col=lane&15, row=(lane>>4)*4+reg
  int node = n0 + (col >> 3), t = col & 7;
  float* ob = out + (size_t)node * 512 + t;
  f32x4 av[4] = {acc0, acc1, acc2, acc3};
#pragma unroll
  for (int mt = 0; mt < 4; ++mt) {
#pragma unroll
    for (int r = 0; r < 4; ++r) {
      int d = mt * 16 + q * 4 + r;
      ob[d * 8] = av[mt][r] + bias[d];
    }
  }
}

extern "C" void kernel_launch(void* const* d_in, const int* in_sizes, int n_in,
                              void* d_out, int out_size, void* d_ws, size_t ws_size,
                              hipStream_t stream) {
  const float* x     = (const float*)d_in[0];
  const int*   ei    = (const int*)d_in[1];
  const float* gamma = (const float*)d_in[2];
  const float* beta  = (const float*)d_in[3];
  const float* W0    = (const float*)d_in[4];
  const float* W1    = (const float*)d_in[5];
  const float* bias  = (const float*)d_in[6];
  float* out = (float*)d_out;

  char* ws = (char*)d_ws;
  size_t off = 0;
  auto alloc = [&](size_t bytes) -> void* {
    void* p = ws + off;
    off = (off + bytes + 255) & ~(size_t)255;
    return p;
  };
  double* dsum = (double*)alloc(128 * NB_STATS * 8);
  double* dsq  = (double*)alloc(128 * NB_STATS * 8);
  double* adbl = (double*)alloc(128 * 8);
  double* bdbl = (double*)alloc(128 * 8);
  int*    deg  = (int*)alloc(N_NODES * 4);
  float*  dinv = (float*)alloc(N_NODES * 4);
  int*    offs = (int*)alloc((N_NODES + 1) * 4);
  int*    curs = (int*)alloc(N_NODES * 4);
  int*    csr  = (int*)alloc(NE * 4);
  unsigned char* spk = (unsigned char*)alloc((size_t)N_NODES * C_IN);
  unsigned short* WTb = (unsigned short*)alloc(2048 * 8 * 2);

  hipMemsetAsync(deg, 0, N_NODES * 4, stream);

  stats_kernel<<<NB_STATS, 256, 0, stream>>>(x, dsum, dsq);
  finalize_kernel<<<128, 256, 0, stream>>>(dsum, dsq, gamma, beta, adbl, bdbl);
  lif_kernel<<<(N_NODES * C_IN) / 256, 256, 0, stream>>>(x, adbl, bdbl, spk);
  deg_kernel<<<(NE + 255) / 256, 256, 0, stream>>>(ei, deg);
  scan_kernel<<<1, 1024, 0, stream>>>(deg, offs, curs, dinv);
  fill_kernel<<<(NE + 255) / 256, 256, 0, stream>>>(ei, curs, csr);
  wtb_kernel<<<8, 256, 0, stream>>>(W0, W1, WTb);
  main_kernel<<<N_NODES / NPB, 256, 0, stream>>>(spk, offs, csr, dinv, WTb, bias, out);
}

// Round 3
// 235.769 us; speedup vs baseline: 1.7438x; 1.1075x over previous
//
#include <hip/hip_runtime.h>
#include <stdint.h>
#include <math.h>

#define N_NODES 20000
#define C_IN 128
#define C_OUT 64
#define T_STEPS 8
#define NE 160000
#define NB_STATS 1024
#define NB_DEG ((NE + 255) / 256)
#define NPB 8        // nodes per block in main kernel
#define RPAD 264     // Bls row stride (bf16 units): 256 + 8 pad

typedef __attribute__((ext_vector_type(8))) short short8;
typedef __attribute__((ext_vector_type(4))) float f32x4;

static __device__ __forceinline__ unsigned short bf16_rne(float f) {
  unsigned u = __builtin_bit_cast(unsigned, f);
  return (unsigned short)((u + 0x7FFFu + ((u >> 16) & 1u)) >> 16);
}

// ---------------- K1: per-channel partial sums (fp64) + degree count (fused) ----------------
__global__ __launch_bounds__(256) void stats_deg_kernel(const float* __restrict__ x,
                                                        double* __restrict__ dsum,
                                                        double* __restrict__ dsq,
                                                        const int* __restrict__ ei,
                                                        int* __restrict__ deg) {
  int tid = threadIdx.x;
  if (blockIdx.x >= NB_STATS) {
    int e = (blockIdx.x - NB_STATS) * 256 + tid;
    if (e < NE) atomicAdd(&deg[ei[NE + e]], 1);
    return;
  }
  const int P = N_NODES * C_IN;
  int gid = blockIdx.x * 256 + tid;
  double s = 0.0, q = 0.0;
  for (int p = gid; p < P; p += 256 * NB_STATS) {  // stride % 128 == 0 -> c constant
    const float4* xp = (const float4*)(x + (size_t)p * 8);
    float4 a = xp[0], b = xp[1];
    float v[8] = {a.x, a.y, a.z, a.w, b.x, b.y, b.z, b.w};
#pragma unroll
    for (int j = 0; j < 8; ++j) { double d = (double)v[j]; s += d; q += d * d; }
  }
  __shared__ double ls[256], lq[256];
  ls[tid] = s; lq[tid] = q;
  __syncthreads();
  if (tid < 128) {  // tid and tid+128 share channel c==tid
    dsum[tid * NB_STATS + blockIdx.x] = ls[tid] + ls[tid + 128];
    dsq [tid * NB_STATS + blockIdx.x] = lq[tid] + lq[tid + 128];
  }
}

// ---------------- K2: finalize per-channel scale/shift + WTb build (fused) ----------------
// WTb layout: [(mt*8+kt)*64 + lane] * 8 bf16 ; A[m][k], m=mt*16+(lane&15), k=kt*32+(lane>>4)*8+j
__global__ __launch_bounds__(256) void finalize_wtb_kernel(const double* __restrict__ dsum,
                                                           const double* __restrict__ dsq,
                                                           const float* __restrict__ gamma,
                                                           const float* __restrict__ beta,
                                                           double* __restrict__ adbl,
                                                           double* __restrict__ bdbl,
                                                           const float* __restrict__ W0,
                                                           const float* __restrict__ W1,
                                                           unsigned short* __restrict__ WTb) {
  int tid = threadIdx.x;
  if (blockIdx.x >= 128) {
    int idx = (blockIdx.x - 128) * 256 + tid;  // 2048 threads
    int mt = idx >> 9, kt = (idx >> 6) & 7, lane = idx & 63;
    int m = mt * 16 + (lane & 15);
    int kb = kt * 32 + (lane >> 4) * 8;
    unsigned short frag[8];
#pragma unroll
    for (int j = 0; j < 8; ++j) {
      int k = kb + j;
      float wv = (k < 128) ? W0[m * 128 + k] : W1[m * 128 + (k - 128)];
      frag[j] = bf16_rne(wv);
    }
    *(uint4*)&WTb[(size_t)idx * 8] = *(uint4*)frag;
    return;
  }
  int c = blockIdx.x;
  __shared__ double ls[256], lq[256];
  double s = 0.0, q = 0.0;
#pragma unroll
  for (int i = 0; i < NB_STATS / 256; ++i) {
    s += dsum[c * NB_STATS + tid + 256 * i];
    q += dsq [c * NB_STATS + tid + 256 * i];
  }
  ls[tid] = s; lq[tid] = q;
  __syncthreads();
  for (int o = 128; o > 0; o >>= 1) {
    if (tid < o) { ls[tid] += ls[tid + o]; lq[tid] += lq[tid + o]; }
    __syncthreads();
  }
  if (tid == 0) {
    const double cnt = (double)N_NODES * T_STEPS;
    double mean = ls[0] / cnt;
    double var  = lq[0] / cnt - mean * mean;
    double ai = (double)gamma[c] / sqrt(var + 1e-5);
    adbl[c] = ai;
    bdbl[c] = (double)beta[c] - mean * ai;
  }
}

// ---------------- K3: LIF recurrence (fp64) + bit-pack spikes ----------------
__global__ __launch_bounds__(256) void lif_kernel(const float* __restrict__ x,
                                                  const double* __restrict__ adbl,
                                                  const double* __restrict__ bdbl,
                                                  unsigned char* __restrict__ spk) {
  int p = blockIdx.x * 256 + threadIdx.x;  // exactly N*C threads
  int c = p & (C_IN - 1);
  const float4* xp = (const float4*)(x + (size_t)p * 8);
  float4 a4 = xp[0], b4 = xp[1];
  float v[8] = {a4.x, a4.y, a4.z, a4.w, b4.x, b4.y, b4.z, b4.w};
  double a = adbl[c], bb = bdbl[c];
  double mem = 0.0, sp = 0.0;
  unsigned byte = 0;
#pragma unroll
  for (int t = 0; t < 8; ++t) {
    double h = a * (double)v[t] + bb;
    mem = mem * (0.2 * (1.0 - sp)) + h;
    int fire = mem > 0.5;
    sp = fire ? 1.0 : 0.0;
    byte |= (unsigned)fire << t;
  }
  spk[p] = (unsigned char)byte;
}

// ---------------- K4: scan (single block, 1 barrier) + dinv ----------------
__global__ __launch_bounds__(1024) void scan_kernel(const int* __restrict__ deg,
                                                    int* __restrict__ offs,
                                                    int* __restrict__ cursor,
                                                    float* __restrict__ dinv) {
  int tid = threadIdx.x, lane = tid & 63, w = tid >> 6;
  int base = tid * 20;  // 1024*20 >= 20000
  int v[20];
  int s = 0;
#pragma unroll
  for (int i = 0; i < 20; ++i) {
    int n = base + i;
    int d = (n < N_NODES) ? deg[n] : 0;
    v[i] = d; s += d;
  }
  int p = s;
#pragma unroll
  for (int o = 1; o < 64; o <<= 1) {
    int u = __shfl_up(p, o);
    if (lane >= o) p += u;
  }
  __shared__ int wsum[16];
  if (lane == 63) wsum[w] = p;
  __syncthreads();
  int wpre = 0;
  for (int j = 0; j < w; ++j) wpre += wsum[j];
  int excl = wpre + p - s;
#pragma unroll
  for (int i = 0; i < 20; ++i) {
    int n = base + i;
    if (n < N_NODES) {
      offs[n] = excl; cursor[n] = excl;
      dinv[n] = v[i] > 0 ? (float)(1.0 / sqrt((double)v[i])) : 0.f;
      excl += v[i];
    }
  }
  if (tid == 1023) offs[N_NODES] = excl;  // all v[i]==0 for OOB -> excl == grand total
}

// ---------------- K5: CSR fill ----------------
__global__ __launch_bounds__(256) void fill_kernel(const int* __restrict__ ei,
                                                   int* __restrict__ cursor,
                                                   int* __restrict__ csr) {
  int e = blockIdx.x * 256 + threadIdx.x;
  if (e < NE) {
    int pos = atomicAdd(&cursor[ei[NE + e]], 1);
    csr[pos] = ei[e];
  }
}

// ---------------- K6: fused spike expand + edge aggregate + MFMA GEMM + bias ----------------
// 512 threads = 8 waves; 8 nodes/block, 1 node per wave in Phase B.
__global__ __launch_bounds__(512) void main_kernel(const unsigned char* __restrict__ spk,
                                                   const int* __restrict__ offs,
                                                   const int* __restrict__ csr,
                                                   const float* __restrict__ dinv,
                                                   const unsigned short* __restrict__ WTb,
                                                   const float* __restrict__ bias,
                                                   float* __restrict__ out) {
  __shared__ unsigned short Bls[64 * RPAD];  // [col][k] bf16, col=nl*8+t, k=0..255
  int tid = threadIdx.x;
  int n0 = blockIdx.x * NPB;
  int lane = tid & 63, w = tid >> 6;

  // Phase A: expand own spikes into k in [0,128). 512 tasks = 64 cols x 8 channel-groups.
  {
    int col = tid & 63, cg = tid >> 6;
    int node = n0 + (col >> 3), t = col & 7;
    uint4 u = *(const uint4*)(spk + (size_t)node * 128 + cg * 16);
    unsigned ua[4] = {u.x, u.y, u.z, u.w};
    unsigned ow[8];
#pragma unroll
    for (int i = 0; i < 4; ++i) {
      unsigned vv = (ua[i] >> t) & 0x01010101u;
      unsigned s0 = (vv & 1u)         ? 0x3F80u : 0u;
      unsigned s1 = ((vv >> 8) & 1u)  ? 0x3F800000u : 0u;
      unsigned s2 = ((vv >> 16) & 1u) ? 0x3F80u : 0u;
      unsigned s3 = (vv >> 24)        ? 0x3F800000u : 0u;
      ow[i * 2]     = s0 | s1;
      ow[i * 2 + 1] = s2 | s3;
    }
    uint4 o0 = {ow[0], ow[1], ow[2], ow[3]};
    uint4 o1 = {ow[4], ow[5], ow[6], ow[7]};
    *(uint4*)&Bls[col * RPAD + cg * 16]     = o0;
    *(uint4*)&Bls[col * RPAD + cg * 16 + 8] = o1;
  }

  // Phase B: wave w aggregates node n0+w; lane covers channels 2*lane, 2*lane+1.
  {
    int node = n0 + w;
    int e0 = offs[node], e1 = offs[node + 1];
    const unsigned short* sp16 = (const unsigned short*)spk;
    float acc[16];
#pragma unroll
    for (int j = 0; j < 16; ++j) acc[j] = 0.f;
    int e = e0;
#pragma unroll 1
    for (; e + 4 <= e1; e += 4) {  // 4 edges in flight -> latency chain /4
      int s0 = csr[e], s1 = csr[e + 1], s2 = csr[e + 2], s3 = csr[e + 3];
      float w0 = dinv[s0], w1 = dinv[s1], w2 = dinv[s2], w3 = dinv[s3];
      unsigned b0 = sp16[(size_t)s0 * 64 + lane];
      unsigned b1 = sp16[(size_t)s1 * 64 + lane];
      unsigned b2 = sp16[(size_t)s2 * 64 + lane];
      unsigned b3 = sp16[(size_t)s3 * 64 + lane];
#pragma unroll
      for (int j = 0; j < 16; ++j) {
        acc[j] = fmaf((float)((b0 >> j) & 1u), w0, acc[j]);
        acc[j] = fmaf((float)((b1 >> j) & 1u), w1, acc[j]);
        acc[j] = fmaf((float)((b2 >> j) & 1u), w2, acc[j]);
        acc[j] = fmaf((float)((b3 >> j) & 1u), w3, acc[j]);
      }
    }
#pragma unroll 1
    for (; e < e1; ++e) {
      int src = csr[e];
      float wt = dinv[src];
      unsigned bits = sp16[(size_t)src * 64 + lane];
#pragma unroll
      for (int j = 0; j < 16; ++j)
        acc[j] = fmaf((float)((bits >> j) & 1u), wt, acc[j]);
    }
    float sc = dinv[node];
    int colb = w * 8;
    int c0 = 2 * lane;
#pragma unroll
    for (int t = 0; t < 8; ++t) {
      unsigned pk = (unsigned)bf16_rne(acc[t] * sc) |
                    ((unsigned)bf16_rne(acc[8 + t] * sc) << 16);
      *(unsigned*)&Bls[(colb + t) * RPAD + 128 + c0] = pk;
    }
  }
  __syncthreads();

  // Phase C: D[m=d][n=col] = sum_k WT[m][k] * B[k][n] via 16x16x32 bf16 MFMA.
  // 16 tiles (mt 0..3 x ct 0..3); wave w does (mt=w&3, ct=w>>2) and (mt=w&3, ct=w>>2+2).
  int q = lane >> 4, l16 = lane & 15;
  int mt = w & 3, ct0 = w >> 2, ct1 = ct0 + 2;
  int colA = ct0 * 16 + l16, colB = ct1 * 16 + l16;
  const short8* WT8 = (const short8*)WTb;
  f32x4 acc0 = {0, 0, 0, 0}, acc1 = {0, 0, 0, 0};
#pragma unroll
  for (int kt = 0; kt < 8; ++kt) {
    short8 a = WT8[(mt * 8 + kt) * 64 + lane];
    short8 bA = *(const short8*)&Bls[colA * RPAD + kt * 32 + q * 8];
    short8 bB = *(const short8*)&Bls[colB * RPAD + kt * 32 + q * 8];
    acc0 = __builtin_amdgcn_mfma_f32_16x16x32_bf16(a, bA, acc0, 0, 0, 0);
    acc1 = __builtin_amdgcn_mfma_f32_16x16x32_bf16(a, bB, acc1, 0, 0, 0);
  }

  // Epilogue: C/D layout col=lane&15, row=(lane>>4)*4+reg
  int nodeA = n0 + (colA >> 3), tA = colA & 7;
  int nodeB = n0 + (colB >> 3), tB = colB & 7;
  float* obA = out + (size_t)nodeA * 512 + tA;
  float* obB = out + (size_t)nodeB * 512 + tB;
#pragma unroll
  for (int r = 0; r < 4; ++r) {
    int d = mt * 16 + q * 4 + r;
    float bv = bias[d];
    obA[d * 8] = acc0[r] + bv;
    obB[d * 8] = acc1[r] + bv;
  }
}

extern "C" void kernel_launch(void* const* d_in, const int* in_sizes, int n_in,
                              void* d_out, int out_size, void* d_ws, size_t ws_size,
                              hipStream_t stream) {
  const float* x     = (const float*)d_in[0];
  const int*   ei    = (const int*)d_in[1];
  const float* gamma = (const float*)d_in[2];
  const float* beta  = (const float*)d_in[3];
  const float* W0    = (const float*)d_in[4];
  const float* W1    = (const float*)d_in[5];
  const float* bias  = (const float*)d_in[6];
  float* out = (float*)d_out;

  char* ws = (char*)d_ws;
  size_t off = 0;
  auto alloc = [&](size_t bytes) -> void* {
    void* p = ws + off;
    off = (off + bytes + 255) & ~(size_t)255;
    return p;
  };
  double* dsum = (double*)alloc(128 * NB_STATS * 8);
  double* dsq  = (double*)alloc(128 * NB_STATS * 8);
  double* adbl = (double*)alloc(128 * 8);
  double* bdbl = (double*)alloc(128 * 8);
  int*    deg  = (int*)alloc(N_NODES * 4);
  float*  dinv = (float*)alloc(N_NODES * 4);
  int*    offs = (int*)alloc((N_NODES + 1) * 4);
  int*    curs = (int*)alloc(N_NODES * 4);
  int*    csr  = (int*)alloc(NE * 4);
  unsigned char* spk = (unsigned char*)alloc((size_t)N_NODES * C_IN);
  unsigned short* WTb = (unsigned short*)alloc(2048 * 8 * 2);

  hipMemsetAsync(deg, 0, N_NODES * 4, stream);

  stats_deg_kernel<<<NB_STATS + NB_DEG, 256, 0, stream>>>(x, dsum, dsq, ei, deg);
  finalize_wtb_kernel<<<128 + 8, 256, 0, stream>>>(dsum, dsq, gamma, beta, adbl, bdbl, W0, W1, WTb);
  lif_kernel<<<(N_NODES * C_IN) / 256, 256, 0, stream>>>(x, adbl, bdbl, spk);
  scan_kernel<<<1, 1024, 0, stream>>>(deg, offs, curs, dinv);
  fill_kernel<<<(NE + 255) / 256, 256, 0, stream>>>(ei, curs, csr);
  main_kernel<<<N_NODES / NPB, 512, 0, stream>>>(spk, offs, csr, dinv, WTb, bias, out);
}